// Round 6
// baseline (4787.632 us; speedup 1.0000x reference)
//
#include <hip/hip_runtime.h>

typedef unsigned int uint;

enum { ACT_RELU=0, ACT_SIGMOID=1, ACT_RESBN=2 };

// ---------------- fused GEMM (f32): C = act(A @ W + bias) [+BN/residual] -----
// A:[M,K] row-major, W:[K,N] row-major. Optional second store C2 (same values).
// tile 64x64, BK=16, 256 threads, 4x4 acc/thread. M%64==0, K%16==0.
template<int ACT>
__global__ __launch_bounds__(256) void gemm_fused(
    const float* __restrict__ A, const float* __restrict__ W,
    const float* __restrict__ bias, float* __restrict__ C,
    float* __restrict__ C2, const float* __restrict__ R,
    const float* __restrict__ gamma, const float* __restrict__ beta,
    int M, int N, int K)
{
    __shared__ float As[16][68];
    __shared__ float Bs[16][68];
    const int tx = threadIdx.x, ty = threadIdx.y;
    const int tid = ty*16 + tx;
    const int row0 = blockIdx.y*64, col0 = blockIdx.x*64;
    float acc[4][4] = {};
    for (int k0 = 0; k0 < K; k0 += 16) {
        #pragma unroll
        for (int t = tid; t < 1024; t += 256) {
            int r = t >> 4, c = t & 15;
            As[c][r] = A[(size_t)(row0+r)*K + k0 + c];
        }
        #pragma unroll
        for (int t = tid; t < 1024; t += 256) {
            int kr = t >> 6, c = t & 63;
            int gc = col0 + c;
            Bs[kr][c] = (gc < N) ? W[(size_t)(k0+kr)*N + gc] : 0.f;
        }
        __syncthreads();
        #pragma unroll
        for (int kk = 0; kk < 16; kk++) {
            float a[4], b[4];
            #pragma unroll
            for (int i = 0; i < 4; i++) a[i] = As[kk][ty*4+i];
            #pragma unroll
            for (int j = 0; j < 4; j++) b[j] = Bs[kk][tx*4+j];
            #pragma unroll
            for (int i = 0; i < 4; i++)
                #pragma unroll
                for (int j = 0; j < 4; j++)
                    acc[i][j] += a[i]*b[j];
        }
        __syncthreads();
    }
    const float INVS = 0.99999500003749968f; // 1/sqrt(1+1e-5)
    #pragma unroll
    for (int i = 0; i < 4; i++) {
        int r = row0 + ty*4 + i;
        #pragma unroll
        for (int j = 0; j < 4; j++) {
            int c = col0 + tx*4 + j;
            if (c < N) {
                float v = acc[i][j] + bias[c];
                if (ACT == ACT_RELU) {
                    v = fmaxf(v, 0.f);
                } else if (ACT == ACT_SIGMOID) {
                    v = 1.f/(1.f + expf(-v));
                } else { // RESBN: relu -> *gamma/sqrt(1+eps)+beta -> +R
                    v = fmaxf(v, 0.f);
                    v = v*(gamma[c]*INVS) + beta[c];
                    v += R[(size_t)r*N + c];
                }
                C[(size_t)r*N + c] = v;
                if (C2) C2[(size_t)r*N + c] = v;
            }
        }
    }
}

// ---------------- split-K accumulating GEMM: C += A@W chunk ------------------
__global__ __launch_bounds__(256) void gemm_acc(
    const float* __restrict__ A, const float* __restrict__ W,
    float* __restrict__ C, int M, int N, int K, int kchunk)
{
    __shared__ float As[16][68];
    __shared__ float Bs[16][68];
    const int tx = threadIdx.x, ty = threadIdx.y;
    const int tid = ty*16 + tx;
    const int row0 = blockIdx.y*64, col0 = blockIdx.x*64;
    const int kbeg = blockIdx.z * kchunk, kend = kbeg + kchunk;
    float acc[4][4] = {};
    for (int k0 = kbeg; k0 < kend; k0 += 16) {
        #pragma unroll
        for (int t = tid; t < 1024; t += 256) {
            int r = t >> 4, c = t & 15;
            As[c][r] = A[(size_t)(row0+r)*K + k0 + c];
        }
        #pragma unroll
        for (int t = tid; t < 1024; t += 256) {
            int kr = t >> 6, c = t & 63;
            int gc = col0 + c;
            Bs[kr][c] = (gc < N) ? W[(size_t)(k0+kr)*N + gc] : 0.f;
        }
        __syncthreads();
        #pragma unroll
        for (int kk = 0; kk < 16; kk++) {
            float a[4], b[4];
            #pragma unroll
            for (int i = 0; i < 4; i++) a[i] = As[kk][ty*4+i];
            #pragma unroll
            for (int j = 0; j < 4; j++) b[j] = Bs[kk][tx*4+j];
            #pragma unroll
            for (int i = 0; i < 4; i++)
                #pragma unroll
                for (int j = 0; j < 4; j++)
                    acc[i][j] += a[i]*b[j];
        }
        __syncthreads();
    }
    #pragma unroll
    for (int i = 0; i < 4; i++) {
        int r = row0 + ty*4 + i;
        #pragma unroll
        for (int j = 0; j < 4; j++) {
            int c = col0 + tx*4 + j;
            if (c < N) atomicAdd(&C[(size_t)r*N + c], acc[i][j]);
        }
    }
}

// ---------------- epilogue for split-K results -------------------------------
template<int ACT>
__global__ __launch_bounds__(256) void epi_k(
    float* __restrict__ C, const float* __restrict__ bias,
    float* __restrict__ dst, int M, int N)
{
    int i = blockIdx.x*256 + threadIdx.x;
    if (i >= M*N) return;
    int c = i % N;
    float v = C[i] + bias[c];
    if (ACT == ACT_RELU) v = fmaxf(v, 0.f);
    else v = 1.f/(1.f + expf(-v));
    C[i] = v;
    if (dst) dst[i] = v;
}

__global__ __launch_bounds__(256) void zero_k(float* __restrict__ p, int n)
{
    int i = blockIdx.x*256 + threadIdx.x;
    if (i < n) p[i] = 0.f;
}

// ---------------- VQ table precompute ----------------------------------------
// dist(z,k) = ||e(z)-E_k||^2 - ||e||^2  (constant-per-element term dropped,
// as in all prior passing rounds) = C2[k] + sum_i a_i(z)*Hm2[k][i]
//   C2[k]  = Esq[k] - 2*dot(bt2, E_k)
//   Hm2[k][i] = -2*dot(Wt2[i,:], E_k)
__global__ __launch_bounds__(256) void esq2_k(
    const float* __restrict__ E, const float* __restrict__ bt2,
    const float* __restrict__ Wt2,
    float* __restrict__ C2, float* __restrict__ Hm2)
{
    int k = blockIdx.x*256 + threadIdx.x;
    if (k >= 512) return;
    const float4* Er = (const float4*)(E + (size_t)k*64);
    const float4* b4 = (const float4*)bt2;
    float esq = 0.f, g0 = 0.f;
    #pragma unroll
    for (int m = 0; m < 16; m++) {
        float4 w = Er[m]; float4 b = b4[m];
        esq += w.x*w.x + w.y*w.y + w.z*w.z + w.w*w.w;
        g0  += b.x*w.x + b.y*w.y + b.z*w.z + b.w*w.w;
    }
    C2[k] = esq - 2.f*g0;
    for (int i = 0; i < 32; i++) {
        const float4* Wr = (const float4*)(Wt2 + i*64);
        float h = 0.f;
        #pragma unroll
        for (int m = 0; m < 16; m++) {
            float4 w = Er[m]; float4 ww = Wr[m];
            h += w.x*ww.x + w.y*ww.y + w.z*ww.z + w.w*ww.w;
        }
        Hm2[(size_t)k*32 + i] = -2.f*h;
    }
}

// ---------------- VQ main: a(z) -> table argmin -> q/loss/counts -------------
// One thread per (b,d) element. The k-loop reads (C2[k], Hm2[k][0..31]) at
// wave-UNIFORM addresses -> scalar-cache s_loads; per-thread state is a[32]
// (all statically indexed, ~55 VGPR incl. overhead -> fits the 64-VGPR /
// 8-wave budget, no spill incentive). Epilogue: exact gather-copy of E[bi],
// e recomputed per element for the (q-e)^2 loss; a[] is staged to LDS
// (column-per-thread, conflict-free, no barrier needed: each thread reads
// only its own column) so the rolled epilogue loop never dynamically
// indexes a register array (round 1-3 scratch lesson).
__global__ __launch_bounds__(256) void vqh_k(
    const float* __restrict__ zencf, const float* __restrict__ Wt1,
    const float* __restrict__ bt1, const float* __restrict__ bt2,
    const float* __restrict__ Wt2, const float* __restrict__ E,
    const float* __restrict__ C2, const float* __restrict__ Hm2,
    float* __restrict__ qout, float* __restrict__ sumsq,
    float* __restrict__ counts)
{
    __shared__ float aT[32][256];
    const int tid = threadIdx.x;
    const int gid = blockIdx.x*256 + tid;
    const float z = zencf[gid];

    float a[32];
    #pragma unroll
    for (int i = 0; i < 32; i++) {
        a[i] = fmaxf(z*Wt1[i] + bt1[i], 0.f);
        aT[i][tid] = a[i];
    }

    // ---- argmin_k  C2[k] + sum_i a_i * Hm2[k][i]  (first-min tie break) ----
    float best = 3.4e38f; int bi = 0;
    for (int k = 0; k < 512; k++) {
        const float* hp = Hm2 + k*32;   // wave-uniform -> s_load
        float s = C2[k];
        #pragma unroll
        for (int i = 0; i < 32; i++) s = fmaf(a[i], hp[i], s);
        if (s < best) { best = s; bi = k; }
    }
    atomicAdd(&counts[bi], 1.f);

    // ---- q = E[bi] exact copy; e recomputed for (q-e)^2; wave-reduce -------
    float ls = 0.f;
    const float4* Eq = (const float4*)(E + (size_t)bi*64);
    const float4* b4 = (const float4*)bt2;
    float2* qo2 = (float2*)(qout + (size_t)gid*64);   // 8B-aligned base
    for (int m = 0; m < 16; m++) {
        float4 w = Eq[m];
        qo2[2*m+0] = make_float2(w.x, w.y);
        qo2[2*m+1] = make_float2(w.z, w.w);
        float4 e4 = b4[m];
        #pragma unroll 8
        for (int i = 0; i < 32; i++) {
            float ai = aT[i][tid];
            float4 wr = *(const float4*)(Wt2 + i*64 + 4*m);  // uniform -> s_load
            e4.x = fmaf(ai, wr.x, e4.x);
            e4.y = fmaf(ai, wr.y, e4.y);
            e4.z = fmaf(ai, wr.z, e4.z);
            e4.w = fmaf(ai, wr.w, e4.w);
        }
        float d;
        d = w.x - e4.x; ls += d*d;
        d = w.y - e4.y; ls += d*d;
        d = w.z - e4.z; ls += d*d;
        d = w.w - e4.w; ls += d*d;
    }
    #pragma unroll
    for (int off = 32; off > 0; off >>= 1)
        ls += __shfl_down(ls, off, 64);
    if ((tid & 63) == 0) atomicAdd(sumsq, ls);
}

// ---------------- losses / perplexity ---------------------------------------
__global__ __launch_bounds__(512) void finalize_k(
    const float* __restrict__ sumsq, const float* __restrict__ counts,
    float* __restrict__ out)
{
    __shared__ float red[512];
    int tid = threadIdx.x;
    float p = counts[tid] * (1.f/262144.f);
    red[tid] = p * logf(p + 1e-10f);
    __syncthreads();
    for (int s = 256; s > 0; s >>= 1) { if (tid < s) red[tid] += red[tid+s]; __syncthreads(); }
    if (tid == 0) {
        out[0]       = 1.25f * sumsq[0] * (1.f/16777216.f); // vq_loss = (1+0.25)*mse
        out[2097153] = expf(-red[0]);                        // perplexity
    }
}

extern "C" void kernel_launch(void* const* d_in, const int* in_sizes, int n_in,
                              void* d_out, int out_size, void* d_ws, size_t ws_size,
                              hipStream_t stream)
{
    // Reference dtypes are float32 throughout -> all inputs/outputs are f32.
    const float* x    = (const float*)d_in[0];
    const float* We1  = (const float*)d_in[1];  const float* be1  = (const float*)d_in[2];
    const float* We2  = (const float*)d_in[3];  const float* be2  = (const float*)d_in[4];
    const float* Wre1 = (const float*)d_in[5];  const float* bre1 = (const float*)d_in[6];
    const float* Wre2 = (const float*)d_in[7];  const float* bre2 = (const float*)d_in[8];
    const float* ge   = (const float*)d_in[9];  const float* bebn = (const float*)d_in[10];
    const float* E    = (const float*)d_in[11];
    const float* Wt1  = (const float*)d_in[12]; const float* bt1  = (const float*)d_in[13];
    const float* Wt2  = (const float*)d_in[14]; const float* bt2  = (const float*)d_in[15];
    const float* Wc   = (const float*)d_in[16]; const float* bc   = (const float*)d_in[17];
    const float* Wp   = (const float*)d_in[18]; const float* bp   = (const float*)d_in[19];
    const float* Wrd1 = (const float*)d_in[20]; const float* brd1 = (const float*)d_in[21];
    const float* Wrd2 = (const float*)d_in[22]; const float* brd2 = (const float*)d_in[23];
    const float* gd   = (const float*)d_in[24]; const float* bdbn = (const float*)d_in[25];
    const float* Wd1  = (const float*)d_in[26]; const float* bd1  = (const float*)d_in[27];
    const float* Wd2  = (const float*)d_in[28]; const float* bd2  = (const float*)d_in[29];

    // f32 output, flat: vq_loss[1] | x_recon[2097152] | ppl[1] | q_st[16777216]
    //                  | cls[5120] | zenc[262144]
    float* out    = (float*)d_out;
    float* o_xr   = out + 1;
    float* o_q    = out + 2097154;
    float* o_cls  = out + 18874370;
    float* o_zenc = out + 18879490;

    // ws (floats): small zeroed buffers first; total ~8.5 MB.
    float* ws    = (float*)d_ws;
    float* sumsq = ws + 0;        // 1      [zeroed]
    float* cnts  = ws + 16;       // 512    [zeroed]
    float* t1    = ws + 528;      // 8192   [zeroed]
    float* t2    = ws + 8720;     // 8192   [zeroed]
    float* clsf  = ws + 16912;    // 5120   [zeroed]
    float* z0    = ws + 22032;    // 262144 [zeroed]
    float* dp0   = ws + 284176;   // 262144 [zeroed]
    float* zencf = ws + 546320;   // 262144
    float* dd    = ws + 808464;   // 262144
    float* hbuf  = ws + 1070608;  // 1048576 (dead between We2-gemm and d2)
    float* d2    = ws + 1070608;
    // VQ tables alias hbuf: written by esq2_k AFTER the We2 gemm consumed
    // hbuf, read by vqh_k, dead before the Wd1 gemm overwrites d2.
    float* c2t   = ws + 1070608;  // 512
    float* hm2t  = ws + 1071120;  // 16384

    dim3 blk(16, 16);

    zero_k<<<dim3(2135), dim3(256), 0, stream>>>(ws, 546320);

    // ---- encoder ----
    gemm_fused<ACT_RELU><<<dim3(32, 8), blk, 0, stream>>>(
        x, We1, be1, hbuf, nullptr, nullptr, nullptr, nullptr, 512, 2048, 4096);
    gemm_acc<<<dim3(8, 8, 4), blk, 0, stream>>>(hbuf, We2, z0, 512, 512, 2048, 512);
    epi_k<ACT_RELU><<<dim3(1024), dim3(256), 0, stream>>>(z0, be2, nullptr, 512, 512);
    gemm_acc<<<dim3(1, 8, 32), blk, 0, stream>>>(z0, Wre1, t1, 512, 16, 512, 16);
    epi_k<ACT_RELU><<<dim3(32), dim3(256), 0, stream>>>(t1, bre1, nullptr, 512, 16);
    gemm_fused<ACT_RESBN><<<dim3(8, 8), blk, 0, stream>>>(
        t1, Wre2, bre2, zencf, o_zenc, z0, ge, bebn, 512, 512, 16);

    // ---- vector quantizer ----
    esq2_k<<<dim3(2), dim3(256), 0, stream>>>(E, bt2, Wt2, c2t, hm2t);
    vqh_k<<<dim3(1024), dim3(256), 0, stream>>>(zencf, Wt1, bt1, bt2, Wt2, E,
                                                c2t, hm2t, o_q, sumsq, cnts);
    finalize_k<<<dim3(1), dim3(512), 0, stream>>>(sumsq, cnts, out);

    // ---- classifier head ----
    gemm_acc<<<dim3(1, 8, 32), blk, 0, stream>>>(o_q, Wc, clsf, 512, 10, 32768, 1024);
    epi_k<ACT_SIGMOID><<<dim3(20), dim3(256), 0, stream>>>(clsf, bc, o_cls, 512, 10);

    // ---- decoder ----
    gemm_acc<<<dim3(8, 8, 8), blk, 0, stream>>>(o_q, Wp, dp0, 512, 512, 32768, 4096);
    epi_k<ACT_RELU><<<dim3(1024), dim3(256), 0, stream>>>(dp0, bp, nullptr, 512, 512);
    gemm_acc<<<dim3(1, 8, 32), blk, 0, stream>>>(dp0, Wrd1, t2, 512, 16, 512, 16);
    epi_k<ACT_RELU><<<dim3(32), dim3(256), 0, stream>>>(t2, brd1, nullptr, 512, 16);
    gemm_fused<ACT_RESBN><<<dim3(8, 8), blk, 0, stream>>>(
        t2, Wrd2, brd2, dd, nullptr, dp0, gd, bdbn, 512, 512, 16);
    gemm_fused<ACT_RELU><<<dim3(32, 8), blk, 0, stream>>>(
        dd, Wd1, bd1, d2, nullptr, nullptr, nullptr, nullptr, 512, 2048, 512);
    gemm_fused<ACT_RELU><<<dim3(64, 8), blk, 0, stream>>>(
        d2, Wd2, bd2, o_xr, nullptr, nullptr, nullptr, nullptr, 512, 4096, 2048);
}

// Round 7
// 4709.074 us; speedup vs baseline: 1.0167x; 1.0167x over previous
//
#include <hip/hip_runtime.h>

typedef unsigned int uint;

enum { ACT_RELU=0, ACT_SIGMOID=1, ACT_RESBN=2 };

// ---------------- fused GEMM (f32): C = act(A @ W + bias) [+BN/residual] -----
// A:[M,K] row-major, W:[K,N] row-major. Optional second store C2 (same values).
// tile 64x64, BK=16, 256 threads, 4x4 acc/thread. M%64==0, K%16==0.
template<int ACT>
__global__ __launch_bounds__(256) void gemm_fused(
    const float* __restrict__ A, const float* __restrict__ W,
    const float* __restrict__ bias, float* __restrict__ C,
    float* __restrict__ C2, const float* __restrict__ R,
    const float* __restrict__ gamma, const float* __restrict__ beta,
    int M, int N, int K)
{
    __shared__ float As[16][68];
    __shared__ float Bs[16][68];
    const int tx = threadIdx.x, ty = threadIdx.y;
    const int tid = ty*16 + tx;
    const int row0 = blockIdx.y*64, col0 = blockIdx.x*64;
    float acc[4][4] = {};
    for (int k0 = 0; k0 < K; k0 += 16) {
        #pragma unroll
        for (int t = tid; t < 1024; t += 256) {
            int r = t >> 4, c = t & 15;
            As[c][r] = A[(size_t)(row0+r)*K + k0 + c];
        }
        #pragma unroll
        for (int t = tid; t < 1024; t += 256) {
            int kr = t >> 6, c = t & 63;
            int gc = col0 + c;
            Bs[kr][c] = (gc < N) ? W[(size_t)(k0+kr)*N + gc] : 0.f;
        }
        __syncthreads();
        #pragma unroll
        for (int kk = 0; kk < 16; kk++) {
            float a[4], b[4];
            #pragma unroll
            for (int i = 0; i < 4; i++) a[i] = As[kk][ty*4+i];
            #pragma unroll
            for (int j = 0; j < 4; j++) b[j] = Bs[kk][tx*4+j];
            #pragma unroll
            for (int i = 0; i < 4; i++)
                #pragma unroll
                for (int j = 0; j < 4; j++)
                    acc[i][j] += a[i]*b[j];
        }
        __syncthreads();
    }
    const float INVS = 0.99999500003749968f; // 1/sqrt(1+1e-5)
    #pragma unroll
    for (int i = 0; i < 4; i++) {
        int r = row0 + ty*4 + i;
        #pragma unroll
        for (int j = 0; j < 4; j++) {
            int c = col0 + tx*4 + j;
            if (c < N) {
                float v = acc[i][j] + bias[c];
                if (ACT == ACT_RELU) {
                    v = fmaxf(v, 0.f);
                } else if (ACT == ACT_SIGMOID) {
                    v = 1.f/(1.f + expf(-v));
                } else { // RESBN: relu -> *gamma/sqrt(1+eps)+beta -> +R
                    v = fmaxf(v, 0.f);
                    v = v*(gamma[c]*INVS) + beta[c];
                    v += R[(size_t)r*N + c];
                }
                C[(size_t)r*N + c] = v;
                if (C2) C2[(size_t)r*N + c] = v;
            }
        }
    }
}

// ---------------- split-K accumulating GEMM: C += A@W chunk ------------------
__global__ __launch_bounds__(256) void gemm_acc(
    const float* __restrict__ A, const float* __restrict__ W,
    float* __restrict__ C, int M, int N, int K, int kchunk)
{
    __shared__ float As[16][68];
    __shared__ float Bs[16][68];
    const int tx = threadIdx.x, ty = threadIdx.y;
    const int tid = ty*16 + tx;
    const int row0 = blockIdx.y*64, col0 = blockIdx.x*64;
    const int kbeg = blockIdx.z * kchunk, kend = kbeg + kchunk;
    float acc[4][4] = {};
    for (int k0 = kbeg; k0 < kend; k0 += 16) {
        #pragma unroll
        for (int t = tid; t < 1024; t += 256) {
            int r = t >> 4, c = t & 15;
            As[c][r] = A[(size_t)(row0+r)*K + k0 + c];
        }
        #pragma unroll
        for (int t = tid; t < 1024; t += 256) {
            int kr = t >> 6, c = t & 63;
            int gc = col0 + c;
            Bs[kr][c] = (gc < N) ? W[(size_t)(k0+kr)*N + gc] : 0.f;
        }
        __syncthreads();
        #pragma unroll
        for (int kk = 0; kk < 16; kk++) {
            float a[4], b[4];
            #pragma unroll
            for (int i = 0; i < 4; i++) a[i] = As[kk][ty*4+i];
            #pragma unroll
            for (int j = 0; j < 4; j++) b[j] = Bs[kk][tx*4+j];
            #pragma unroll
            for (int i = 0; i < 4; i++)
                #pragma unroll
                for (int j = 0; j < 4; j++)
                    acc[i][j] += a[i]*b[j];
        }
        __syncthreads();
    }
    #pragma unroll
    for (int i = 0; i < 4; i++) {
        int r = row0 + ty*4 + i;
        #pragma unroll
        for (int j = 0; j < 4; j++) {
            int c = col0 + tx*4 + j;
            if (c < N) atomicAdd(&C[(size_t)r*N + c], acc[i][j]);
        }
    }
}

// ---------------- epilogue for split-K results -------------------------------
template<int ACT>
__global__ __launch_bounds__(256) void epi_k(
    float* __restrict__ C, const float* __restrict__ bias,
    float* __restrict__ dst, int M, int N)
{
    int i = blockIdx.x*256 + threadIdx.x;
    if (i >= M*N) return;
    int c = i % N;
    float v = C[i] + bias[c];
    if (ACT == ACT_RELU) v = fmaxf(v, 0.f);
    else v = 1.f/(1.f + expf(-v));
    C[i] = v;
    if (dst) dst[i] = v;
}

__global__ __launch_bounds__(256) void zero_k(float* __restrict__ p, int n)
{
    int i = blockIdx.x*256 + threadIdx.x;
    if (i < n) p[i] = 0.f;
}

// ---------------- VQ table precompute ----------------------------------------
// dist(z,k) = ||e(z)-E_k||^2 - ||e||^2  (constant-per-element term dropped,
// as in all prior passing rounds) = C2[k] + sum_i a_i(z)*Hm2[k][i]
//   C2[k]  = Esq[k] - 2*dot(bt2, E_k)
//   Hm2[k][i] = -2*dot(Wt2[i,:], E_k)
__global__ __launch_bounds__(256) void esq2_k(
    const float* __restrict__ E, const float* __restrict__ bt2,
    const float* __restrict__ Wt2,
    float* __restrict__ C2, float* __restrict__ Hm2)
{
    int k = blockIdx.x*256 + threadIdx.x;
    if (k >= 512) return;
    const float4* Er = (const float4*)(E + (size_t)k*64);
    const float4* b4 = (const float4*)bt2;
    float esq = 0.f, g0 = 0.f;
    #pragma unroll
    for (int m = 0; m < 16; m++) {
        float4 w = Er[m]; float4 b = b4[m];
        esq += w.x*w.x + w.y*w.y + w.z*w.z + w.w*w.w;
        g0  += b.x*w.x + b.y*w.y + b.z*w.z + b.w*w.w;
    }
    C2[k] = esq - 2.f*g0;
    for (int i = 0; i < 32; i++) {
        const float4* Wr = (const float4*)(Wt2 + i*64);
        float h = 0.f;
        #pragma unroll
        for (int m = 0; m < 16; m++) {
            float4 w = Er[m]; float4 ww = Wr[m];
            h += w.x*ww.x + w.y*ww.y + w.z*ww.z + w.w*ww.w;
        }
        Hm2[(size_t)k*32 + i] = -2.f*h;
    }
}

// ---------------- VQ main: a(z) -> LDS-table argmin -> q/loss/counts ---------
// Round-6 diagnosis: with tables in GLOBAL memory, the 64KB Hm2 stream was
// continuously evicted from L2 by the concurrent qout/E traffic -> 1.2 GB of
// HBM fetches, one ~900-cycle latency per code iteration, 2215 us at 6%
// VALUBusy. Fix: stage Hm2(64KB)+C2(2KB)+Wt2(8KB) in LDS once per block.
// The k-loop is then pure {uniform-broadcast ds_read_b128 + v_fmaf}: zero
// global ops, zero bank conflicts (uniform address = broadcast). 74KB LDS
// -> 2 blocks/CU; amdgpu_waves_per_eu(2,2) matches that cap and gives the
// allocator a 128-VGPR budget (demand ~60, no spill incentive; round-6
// VGPR=44 proved a[32] fits in regs). Distance expression, fmaf order,
// table values, and first-min tie-break are BITWISE IDENTICAL to the
// round-6 passing kernel -- only the storage tier of the table reads moved.
__global__ __launch_bounds__(256)
__attribute__((amdgpu_waves_per_eu(2, 2)))
void vql_k(
    const float* __restrict__ zencf, const float* __restrict__ Wt1,
    const float* __restrict__ bt1, const float* __restrict__ bt2,
    const float* __restrict__ Wt2, const float* __restrict__ E,
    const float* __restrict__ C2, const float* __restrict__ Hm2,
    float* __restrict__ qout, float* __restrict__ sumsq,
    float* __restrict__ counts)
{
    __shared__ float HmS[16384];   // 512 codes x 32  (64 KB)
    __shared__ float C2s[512];     // 2 KB
    __shared__ float Wt2s[2048];   // 32 x 64 (8 KB)
    const int tid = threadIdx.x;
    const int gid = blockIdx.x*256 + tid;

    // ---- stage tables (coalesced float4) ----
    {
        const float4* src = (const float4*)Hm2;
        float4* dst = (float4*)HmS;
        #pragma unroll
        for (int t = 0; t < 16; t++) dst[t*256 + tid] = src[t*256 + tid];
        const float4* ws2 = (const float4*)Wt2;
        float4* wd2 = (float4*)Wt2s;
        #pragma unroll
        for (int t = 0; t < 2; t++) wd2[t*256 + tid] = ws2[t*256 + tid];
        #pragma unroll
        for (int t = 0; t < 2; t++) C2s[t*256 + tid] = C2[t*256 + tid];
    }
    const float z = zencf[gid];
    __syncthreads();

    // ---- a_i = relu(z*Wt1[i]+bt1[i]), statically indexed registers ----
    float a[32];
    #pragma unroll
    for (int i = 0; i < 32; i++)
        a[i] = fmaxf(z*Wt1[i] + bt1[i], 0.f);

    // ---- argmin_k  C2[k] + sum_i a_i * Hm2[k][i]  (first-min tie break) ----
    float best = 3.4e38f; int bi = 0;
    for (int k = 0; k < 512; k++) {
        const float4* hp4 = (const float4*)(HmS + (k << 5)); // wave-uniform -> broadcast
        float s = C2s[k];
        #pragma unroll
        for (int j = 0; j < 8; j++) {
            float4 h = hp4[j];
            s = fmaf(a[4*j+0], h.x, s);
            s = fmaf(a[4*j+1], h.y, s);
            s = fmaf(a[4*j+2], h.z, s);
            s = fmaf(a[4*j+3], h.w, s);
        }
        if (s < best) { best = s; bi = k; }
    }
    atomicAdd(&counts[bi], 1.f);

    // ---- q = E[bi] exact copy; e recomputed for (q-e)^2; wave-reduce -------
    float ls = 0.f;
    const float4* Eq = (const float4*)(E + (size_t)bi*64);
    const float4* b4 = (const float4*)bt2;
    float2* qo2 = (float2*)(qout + (size_t)gid*64);   // 8B-aligned base
    for (int m = 0; m < 16; m++) {
        float4 w = Eq[m];
        qo2[2*m+0] = make_float2(w.x, w.y);
        qo2[2*m+1] = make_float2(w.z, w.w);
        float4 e4 = b4[m];
        #pragma unroll
        for (int i = 0; i < 32; i++) {
            float4 wr = *(const float4*)(Wt2s + i*64 + 4*m);  // uniform -> broadcast
            e4.x = fmaf(a[i], wr.x, e4.x);
            e4.y = fmaf(a[i], wr.y, e4.y);
            e4.z = fmaf(a[i], wr.z, e4.z);
            e4.w = fmaf(a[i], wr.w, e4.w);
        }
        float d;
        d = w.x - e4.x; ls += d*d;
        d = w.y - e4.y; ls += d*d;
        d = w.z - e4.z; ls += d*d;
        d = w.w - e4.w; ls += d*d;
    }
    #pragma unroll
    for (int off = 32; off > 0; off >>= 1)
        ls += __shfl_down(ls, off, 64);
    if ((tid & 63) == 0) atomicAdd(sumsq, ls);
}

// ---------------- losses / perplexity ---------------------------------------
__global__ __launch_bounds__(512) void finalize_k(
    const float* __restrict__ sumsq, const float* __restrict__ counts,
    float* __restrict__ out)
{
    __shared__ float red[512];
    int tid = threadIdx.x;
    float p = counts[tid] * (1.f/262144.f);
    red[tid] = p * logf(p + 1e-10f);
    __syncthreads();
    for (int s = 256; s > 0; s >>= 1) { if (tid < s) red[tid] += red[tid+s]; __syncthreads(); }
    if (tid == 0) {
        out[0]       = 1.25f * sumsq[0] * (1.f/16777216.f); // vq_loss = (1+0.25)*mse
        out[2097153] = expf(-red[0]);                        // perplexity
    }
}

extern "C" void kernel_launch(void* const* d_in, const int* in_sizes, int n_in,
                              void* d_out, int out_size, void* d_ws, size_t ws_size,
                              hipStream_t stream)
{
    // Reference dtypes are float32 throughout -> all inputs/outputs are f32.
    const float* x    = (const float*)d_in[0];
    const float* We1  = (const float*)d_in[1];  const float* be1  = (const float*)d_in[2];
    const float* We2  = (const float*)d_in[3];  const float* be2  = (const float*)d_in[4];
    const float* Wre1 = (const float*)d_in[5];  const float* bre1 = (const float*)d_in[6];
    const float* Wre2 = (const float*)d_in[7];  const float* bre2 = (const float*)d_in[8];
    const float* ge   = (const float*)d_in[9];  const float* bebn = (const float*)d_in[10];
    const float* E    = (const float*)d_in[11];
    const float* Wt1  = (const float*)d_in[12]; const float* bt1  = (const float*)d_in[13];
    const float* Wt2  = (const float*)d_in[14]; const float* bt2  = (const float*)d_in[15];
    const float* Wc   = (const float*)d_in[16]; const float* bc   = (const float*)d_in[17];
    const float* Wp   = (const float*)d_in[18]; const float* bp   = (const float*)d_in[19];
    const float* Wrd1 = (const float*)d_in[20]; const float* brd1 = (const float*)d_in[21];
    const float* Wrd2 = (const float*)d_in[22]; const float* brd2 = (const float*)d_in[23];
    const float* gd   = (const float*)d_in[24]; const float* bdbn = (const float*)d_in[25];
    const float* Wd1  = (const float*)d_in[26]; const float* bd1  = (const float*)d_in[27];
    const float* Wd2  = (const float*)d_in[28]; const float* bd2  = (const float*)d_in[29];

    // f32 output, flat: vq_loss[1] | x_recon[2097152] | ppl[1] | q_st[16777216]
    //                  | cls[5120] | zenc[262144]
    float* out    = (float*)d_out;
    float* o_xr   = out + 1;
    float* o_q    = out + 2097154;
    float* o_cls  = out + 18874370;
    float* o_zenc = out + 18879490;

    // ws (floats): small zeroed buffers first; total ~8.5 MB.
    float* ws    = (float*)d_ws;
    float* sumsq = ws + 0;        // 1      [zeroed]
    float* cnts  = ws + 16;       // 512    [zeroed]
    float* t1    = ws + 528;      // 8192   [zeroed]
    float* t2    = ws + 8720;     // 8192   [zeroed]
    float* clsf  = ws + 16912;    // 5120   [zeroed]
    float* z0    = ws + 22032;    // 262144 [zeroed]
    float* dp0   = ws + 284176;   // 262144 [zeroed]
    float* zencf = ws + 546320;   // 262144
    float* dd    = ws + 808464;   // 262144
    float* hbuf  = ws + 1070608;  // 1048576 (dead between We2-gemm and d2)
    float* d2    = ws + 1070608;
    // VQ tables alias hbuf: written by esq2_k AFTER the We2 gemm consumed
    // hbuf, read by vql_k, dead before the Wd1 gemm overwrites d2.
    float* c2t   = ws + 1070608;  // 512
    float* hm2t  = ws + 1071120;  // 16384

    dim3 blk(16, 16);

    zero_k<<<dim3(2135), dim3(256), 0, stream>>>(ws, 546320);

    // ---- encoder ----
    gemm_fused<ACT_RELU><<<dim3(32, 8), blk, 0, stream>>>(
        x, We1, be1, hbuf, nullptr, nullptr, nullptr, nullptr, 512, 2048, 4096);
    gemm_acc<<<dim3(8, 8, 4), blk, 0, stream>>>(hbuf, We2, z0, 512, 512, 2048, 512);
    epi_k<ACT_RELU><<<dim3(1024), dim3(256), 0, stream>>>(z0, be2, nullptr, 512, 512);
    gemm_acc<<<dim3(1, 8, 32), blk, 0, stream>>>(z0, Wre1, t1, 512, 16, 512, 16);
    epi_k<ACT_RELU><<<dim3(32), dim3(256), 0, stream>>>(t1, bre1, nullptr, 512, 16);
    gemm_fused<ACT_RESBN><<<dim3(8, 8), blk, 0, stream>>>(
        t1, Wre2, bre2, zencf, o_zenc, z0, ge, bebn, 512, 512, 16);

    // ---- vector quantizer ----
    esq2_k<<<dim3(2), dim3(256), 0, stream>>>(E, bt2, Wt2, c2t, hm2t);
    vql_k<<<dim3(1024), dim3(256), 0, stream>>>(zencf, Wt1, bt1, bt2, Wt2, E,
                                                c2t, hm2t, o_q, sumsq, cnts);
    finalize_k<<<dim3(1), dim3(512), 0, stream>>>(sumsq, cnts, out);

    // ---- classifier head ----
    gemm_acc<<<dim3(1, 8, 32), blk, 0, stream>>>(o_q, Wc, clsf, 512, 10, 32768, 1024);
    epi_k<ACT_SIGMOID><<<dim3(20), dim3(256), 0, stream>>>(clsf, bc, o_cls, 512, 10);

    // ---- decoder ----
    gemm_acc<<<dim3(8, 8, 8), blk, 0, stream>>>(o_q, Wp, dp0, 512, 512, 32768, 4096);
    epi_k<ACT_RELU><<<dim3(1024), dim3(256), 0, stream>>>(dp0, bp, nullptr, 512, 512);
    gemm_acc<<<dim3(1, 8, 32), blk, 0, stream>>>(dp0, Wrd1, t2, 512, 16, 512, 16);
    epi_k<ACT_RELU><<<dim3(32), dim3(256), 0, stream>>>(t2, brd1, nullptr, 512, 16);
    gemm_fused<ACT_RESBN><<<dim3(8, 8), blk, 0, stream>>>(
        t2, Wrd2, brd2, dd, nullptr, dp0, gd, bdbn, 512, 512, 16);
    gemm_fused<ACT_RELU><<<dim3(32, 8), blk, 0, stream>>>(
        dd, Wd1, bd1, d2, nullptr, nullptr, nullptr, nullptr, 512, 2048, 512);
    gemm_fused<ACT_RELU><<<dim3(64, 8), blk, 0, stream>>>(
        d2, Wd2, bd2, o_xr, nullptr, nullptr, nullptr, nullptr, 512, 4096, 2048);
}